// Round 3
// baseline (136.772 us; speedup 1.0000x reference)
//
#include <hip/hip_runtime.h>
#include <cstddef>

#define HDIM 2048
#define NE 64
#define TOPK 4
#define BM 64
#define KSPLIT 2
#define KHALF (HDIM / KSPLIT)    // 1024
#define NTHREADS 256
#define SSTRIDE 65

// ---------- pre-pass: wt[k][e] = w[e][k] * scale[k]  (512 KB, ~4 us) ----------
__global__ __launch_bounds__(256) void transpose_w_kernel(
    const float* __restrict__ w, const float* __restrict__ scale,
    float* __restrict__ wt)
{
    int idx = blockIdx.x * 256 + threadIdx.x;   // 0 .. HDIM*NE-1
    int k = idx >> 6;
    int e = idx & 63;
    wt[idx] = w[(size_t)e * HDIM + k] * scale[k];
}

// ---------- main GEMM: A global->reg stream, B via SGPR s_load, no LDS ----------
__global__ __launch_bounds__(NTHREADS) void gemm_smem_kernel(
    const float* __restrict__ x,
    const float* __restrict__ wt,    // [HDIM][NE], scale folded in
    float* __restrict__ sp0,         // partial scores half 0 (probs region)
    float* __restrict__ sp1,         // partial scores half 1 (ws)
    float* __restrict__ sq0,         // partial ssq half 0 (ws)
    float* __restrict__ sq1)         // partial ssq half 1 (ws)
{
    const int tid = threadIdx.x;
    const int lane = tid & 63;                                   // token within tile
    const int eg = __builtin_amdgcn_readfirstlane(tid >> 6);     // expert group 0..3 (uniform)
    const int half = blockIdx.x & 1;
    const int tok0 = (blockIdx.x >> 1) * BM;
    const int tok = tok0 + lane;

    const float4* xrow = (const float4*)(x + (size_t)tok * HDIM + half * KHALF);
    const float* bbase = wt + (size_t)half * KHALF * NE + eg * 16;  // uniform pointer

    float acc[16];
    #pragma unroll
    for (int e = 0; e < 16; e++) acc[e] = 0.f;
    float ssq = 0.f;

    const int NK4 = KHALF / 4;      // 256 float4 steps
    float4 buf[4];
    #pragma unroll
    for (int p = 0; p < 4; p++) buf[p] = xrow[p];

    int k4 = 0;
    #pragma unroll 4
    for (; k4 < NK4 - 4; ++k4) {
        float4 a = buf[k4 & 3];
        buf[k4 & 3] = xrow[k4 + 4];           // prefetch 4 steps ahead
        ssq += a.x*a.x + a.y*a.y + a.z*a.z + a.w*a.w;
        const float* b0 = bbase + (size_t)(4 * k4) * NE;
        #pragma unroll
        for (int j = 0; j < 4; j++) {
            float aj = (j == 0) ? a.x : (j == 1) ? a.y : (j == 2) ? a.z : a.w;
            const float* bj = b0 + j * NE;    // uniform -> s_load_dwordx16
            #pragma unroll
            for (int e = 0; e < 16; e++)
                acc[e] = fmaf(aj, bj[e], acc[e]);
        }
    }
    #pragma unroll 4
    for (; k4 < NK4; ++k4) {                  // epilogue, no prefetch
        float4 a = buf[k4 & 3];
        ssq += a.x*a.x + a.y*a.y + a.z*a.z + a.w*a.w;
        const float* b0 = bbase + (size_t)(4 * k4) * NE;
        #pragma unroll
        for (int j = 0; j < 4; j++) {
            float aj = (j == 0) ? a.x : (j == 1) ? a.y : (j == 2) ? a.z : a.w;
            const float* bj = b0 + j * NE;
            #pragma unroll
            for (int e = 0; e < 16; e++)
                acc[e] = fmaf(aj, bj[e], acc[e]);
        }
    }

    // ssq is fully lane-local (whole K-half per lane); one wave writes it
    if (eg == 0) {
        float* sq = half ? sq1 : sq0;
        sq[tok] = ssq;
    }

    // raw partial scores: 4x float4 per thread
    float* sp = half ? sp1 : sp0;
    float* dst = sp + (size_t)tok * NE + eg * 16;
    #pragma unroll
    for (int q = 0; q < 4; q++) {
        float4 v;
        v.x = acc[4*q + 0]; v.y = acc[4*q + 1];
        v.z = acc[4*q + 2]; v.w = acc[4*q + 3];
        *(float4*)(dst + 4*q) = v;
    }
}

// ---------- finisher: sum partials, rmsnorm factor, softmax, top-4 (proven) ----------
__global__ __launch_bounds__(NTHREADS) void finish_kernel(
    const float* __restrict__ sp0,
    const float* __restrict__ sp1,
    const float* __restrict__ sq0,
    const float* __restrict__ sq1,
    const float* __restrict__ pes,
    float* __restrict__ probs,
    float* __restrict__ tkw,
    float* __restrict__ tki)
{
    __shared__ float Sl[BM * SSTRIDE];
    __shared__ float Pl[BM * SSTRIDE];
    __shared__ float FN[BM];
    __shared__ float RS[BM];

    const int tid = threadIdx.x;
    const int tok0 = blockIdx.x * BM;

    if (tid < BM) {
        float ss = sq0[tok0 + tid] + sq1[tok0 + tid];
        FN[tid] = rsqrtf(ss * (1.0f / HDIM) + 1e-6f) * 0.022097086912079612f; // * H^-0.5
    }
    __syncthreads();

    const float4* a4 = (const float4*)sp0;
    const float4* b4 = (const float4*)sp1;
    #pragma unroll
    for (int q = 0; q < 4; q++) {
        int f = tid + NTHREADS * q;
        int m = f >> 4;
        int e4 = f & 15;
        float4 a = a4[(size_t)(tok0 + m) * (NE/4) + e4];
        float4 b = b4[(size_t)(tok0 + m) * (NE/4) + e4];
        float fn = FN[m];
        int base = m * SSTRIDE + e4 * 4;
        Sl[base + 0] = (a.x + b.x) * fn;
        Sl[base + 1] = (a.y + b.y) * fn;
        Sl[base + 2] = (a.z + b.z) * fn;
        Sl[base + 3] = (a.w + b.w) * fn;
    }
    __syncthreads();

    if (tid < BM) {
        const int m = tid;
        float mx = -3.0e38f;
        for (int e = 0; e < NE; e++) mx = fmaxf(mx, Sl[m * SSTRIDE + e]);
        float sum = 0.f;
        for (int e = 0; e < NE; e++) {
            float p = __expf(Sl[m * SSTRIDE + e] - mx);
            Pl[m * SSTRIDE + e] = p;
            sum += p;
        }
        RS[m] = 1.0f / sum;
    }
    __syncthreads();

    #pragma unroll
    for (int q = 0; q < 4; q++) {
        int f = tid + NTHREADS * q;
        int m = f >> 4;
        int e0 = (f & 15) * 4;
        float rs = RS[m];
        float4 pv;
        pv.x = Pl[m * SSTRIDE + e0 + 0] * rs;
        pv.y = Pl[m * SSTRIDE + e0 + 1] * rs;
        pv.z = Pl[m * SSTRIDE + e0 + 2] * rs;
        pv.w = Pl[m * SSTRIDE + e0 + 3] * rs;
        *(float4*)&probs[(size_t)(tok0 + m) * NE + e0] = pv;
    }

    if (tid < BM) {                          // destructive top-4, lowest-index ties
        const int m = tid;
        float wv[TOPK]; int idx[TOPK];
        float wsum = 0.f;
        #pragma unroll
        for (int kk = 0; kk < TOPK; ++kk) {
            float best = -3.0e38f; int bi = 0;
            for (int e = 0; e < NE; e++) {
                float v = Sl[m * SSTRIDE + e];
                if (v > best) { best = v; bi = e; }
            }
            Sl[m * SSTRIDE + bi] = -3.4e38f;
            float p = Pl[m * SSTRIDE + bi];
            wv[kk] = p; idx[kk] = bi; wsum += p;
        }
        float inv = 1.0f / wsum;
        size_t ob = (size_t)(tok0 + m) * TOPK;
        #pragma unroll
        for (int kk = 0; kk < TOPK; kk++) {
            tkw[ob + kk] = wv[kk] * inv * pes[idx[kk]];
            tki[ob + kk] = (float)idx[kk];   // harness reads flat buffer as float32
        }
    }
}

extern "C" void kernel_launch(void* const* d_in, const int* in_sizes, int n_in,
                              void* d_out, int out_size, void* d_ws, size_t ws_size,
                              hipStream_t stream) {
    const float* x     = (const float*)d_in[0];
    const float* w     = (const float*)d_in[1];
    const float* scale = (const float*)d_in[2];
    const float* pes   = (const float*)d_in[3];
    const int tokens = in_sizes[0] / HDIM;            // 16384

    float* probs = (float*)d_out;
    float* tkw   = probs + (size_t)tokens * NE;
    float* tki   = tkw + (size_t)tokens * TOPK;

    // ws layout: wt (HDIM*NE), sp1 (tokens*NE), sq0 (tokens), sq1 (tokens)
    float* wt  = (float*)d_ws;
    float* sp1 = wt + (size_t)HDIM * NE;
    float* sq0 = sp1 + (size_t)tokens * NE;
    float* sq1 = sq0 + tokens;
    float* sp0 = probs;   // half-0 partial scores live in probs region; finisher overwrites

    transpose_w_kernel<<<(HDIM * NE) / 256, 256, 0, stream>>>(w, scale, wt);

    const int grid1 = (tokens / BM) * KSPLIT;         // 512 -> 2 blocks/CU
    gemm_smem_kernel<<<grid1, NTHREADS, 0, stream>>>(x, wt, sp0, sp1, sq0, sq1);

    const int grid2 = tokens / BM;                    // 256
    finish_kernel<<<grid2, NTHREADS, 0, stream>>>(sp0, sp1, sq0, sq1, pes, probs, tkw, tki);
}